// Round 20
// baseline (136.786 us; speedup 1.0000x reference)
//
#include <hip/hip_runtime.h>
#include <hip/hip_bf16.h>
#include <math.h>

typedef __bf16 bf16_t;
typedef __bf16 bf16x8 __attribute__((ext_vector_type(8)));
typedef __bf16 bf16x4 __attribute__((ext_vector_type(4)));
typedef float f32x4 __attribute__((ext_vector_type(4)));

#define B_DIM 1024
#define D_DIM 1024
#define H_DIM 2048
#define E_DIM 8
#define M_DIM 2048

typedef const __attribute__((address_space(1))) unsigned int as1_uint;
typedef __attribute__((address_space(3))) unsigned int as3_uint;

__device__ __forceinline__ void gl_lds16(const void* g, void* l) {
  __builtin_amdgcn_global_load_lds((as1_uint*)g, (as3_uint*)l, 16, 0, 0);
}

#define WAITV(n) asm volatile("s_waitcnt vmcnt(" #n ")" ::: "memory")

// ---------------- prep: transpose 128x64 (0..3071), gate+cvt (3072..4095) ------------------
__global__ __launch_bounds__(256, 6) void prep_kernel(
    const float* __restrict__ ew, const float* __restrict__ mrw, const float* __restrict__ mem,
    bf16_t* __restrict__ wbT, bf16_t* __restrict__ mrT, bf16_t* __restrict__ memT,
    const float* __restrict__ x, const float* __restrict__ gw,
    float* __restrict__ gate_t, bf16_t* __restrict__ x_bf) {
  __shared__ char smem[16384];
  const int bid = blockIdx.x;
  const int t = threadIdx.x;

  if (bid < 3072) {
    bf16_t* tile = (bf16_t*)smem;   // [128][64] elem, addr = r*64 + (c ^ ((r>>3)&7)<<2)
    const float* in; bf16_t* out; int R, C, rt, ct;
    if (bid < 2048) {
      int slab = bid >> 8, rem = bid & 255;
      in = ew + (size_t)slab * D_DIM * H_DIM; out = wbT + (size_t)slab * D_DIM * H_DIM;
      R = D_DIM; C = H_DIM; rt = rem >> 5; ct = rem & 31;
    } else if (bid < 2560) {
      int rem = bid - 2048;
      in = mrw; out = mrT; R = H_DIM; C = M_DIM; rt = rem >> 5; ct = rem & 31;
    } else {
      int rem = bid - 2560;
      in = mem; out = memT; R = M_DIM; C = H_DIM; rt = rem >> 5; ct = rem & 31;
    }
    const int r0 = rt * 128, c0 = ct * 64;
    int cq = (t & 15) * 4, rr = t >> 4;
#pragma unroll
    for (int i = 0; i < 8; ++i) {
      int r = rr + 16 * i;
      float4 v = *(const float4*)&in[(size_t)(r0 + r) * C + c0 + cq];
      bf16x4 b;
      b[0] = (bf16_t)v.x; b[1] = (bf16_t)v.y; b[2] = (bf16_t)v.z; b[3] = (bf16_t)v.w;
      *(bf16x4*)&tile[r * 64 + (cq ^ (((r >> 3) & 7) << 2))] = b;
    }
    __syncthreads();
    int r8 = (t & 15) * 8, cc = t >> 4;
    const int sw = (t & 7) << 2;   // = ((r8>>3)&7)<<2, constant over j
#pragma unroll
    for (int i = 0; i < 4; ++i) {
      int c = cc + 16 * i;
      bf16x8 o;
#pragma unroll
      for (int j = 0; j < 8; ++j) o[j] = tile[(r8 + j) * 64 + (c ^ sw)];
      *(bf16x8*)&out[(size_t)(c0 + c) * R + r0 + r8] = o;
    }
  } else {
    // gate + x cvt
    float (*red)[8] = (float(*)[8])smem;   // 8 KB
    int b = bid - 3072;
    float4 v = ((const float4*)(x + (size_t)b * D_DIM))[t];
    bf16x4 xb;
    xb[0] = (bf16_t)v.x; xb[1] = (bf16_t)v.y; xb[2] = (bf16_t)v.z; xb[3] = (bf16_t)v.w;
    *(bf16x4*)&x_bf[(size_t)b * D_DIM + t * 4] = xb;
    float acc[8];
#pragma unroll
    for (int e = 0; e < 8; ++e)
      acc[e] = v.x * gw[(4 * t) * 8 + e] + v.y * gw[(4 * t + 1) * 8 + e] +
               v.z * gw[(4 * t + 2) * 8 + e] + v.w * gw[(4 * t + 3) * 8 + e];
#pragma unroll
    for (int e = 0; e < 8; ++e) red[t][e] = acc[e];
    __syncthreads();
    for (int s = 128; s > 0; s >>= 1) {
      if (t < s) {
#pragma unroll
        for (int e = 0; e < 8; ++e) red[t][e] += red[t + s][e];
      }
      __syncthreads();
    }
    if (t == 0) {
      float m = red[0][0];
#pragma unroll
      for (int e = 1; e < 8; ++e) m = fmaxf(m, red[0][e]);
      float p[8], sum = 0.f;
#pragma unroll
      for (int e = 0; e < 8; ++e) { p[e] = expf(red[0][e] - m); sum += p[e]; }
      float inv = 1.f / sum;
#pragma unroll
      for (int e = 0; e < 8; ++e) gate_t[e * B_DIM + b] = p[e] * inv;
    }
  }
}

// ---------------- conn (separate, single dispatch): 64 blocks (e,c); full h1 each ----------
__global__ __launch_bounds__(256) void conn_kernel(
    const float* __restrict__ avg, const float* __restrict__ w1, const float* __restrict__ b1,
    const float* __restrict__ w2, const float* __restrict__ b2,
    const float* __restrict__ mask, float* __restrict__ conn) {
  __shared__ float red[256 * 32];
  __shared__ float h1[32];
  int e = blockIdx.x >> 3, c = blockIdx.x & 7, t = threadIdx.x;
  float acc[32];
#pragma unroll
  for (int k = 0; k < 32; ++k) acc[k] = 0.f;
#pragma unroll
  for (int i = 0; i < 8; ++i) {
    int h = i * 256 + t;
    float av = avg[e * H_DIM + h];
    const float* w1p = &w1[((size_t)e * H_DIM + h) * 32];
#pragma unroll
    for (int k = 0; k < 32; ++k) acc[k] += av * w1p[k];
  }
#pragma unroll
  for (int k = 0; k < 32; ++k) red[t * 32 + k] = acc[k];
  __syncthreads();
  for (int s = 128; s > 0; s >>= 1) {
    if (t < s) {
#pragma unroll
      for (int k = 0; k < 32; ++k) red[t * 32 + k] += red[(t + s) * 32 + k];
    }
    __syncthreads();
  }
  if (t < 32) h1[t] = fmaxf(red[t] + b1[e * 32 + t], 0.f);
  __syncthreads();
  int h = c * 256 + t;
  float s = b2[e * H_DIM + h];
#pragma unroll
  for (int k = 0; k < 32; ++k) s += h1[k] * w2[((size_t)e * 32 + k) * H_DIM + h];
  conn[e * H_DIM + h] = (1.f / (1.f + expf(-s))) * mask[e * H_DIM + h];
}

// ---------------- expert GEMM: 128x64 tile, 8 waves, pair-phase, ring-6, DISTANCE-1 --------
// Stage at pair-phase P loads the pair read at P+1 (slots (2P+2)%6). Slot written at P was
// last read at P-2 (completed before barrier(P-1)) -> race-free. FIFO ledger: prologue
// [A,A,B0,B1]; steady WAITV(2); eh3 non-last WAITV(4) (A-pair + next-pair in flight);
// kt15/eh3 WAITV(0). Each wait retires exactly this phase's loads. LDS 80KB -> 2 blocks/CU.
__global__ __launch_bounds__(512, 2) void expert_gemm(
    const bf16_t* __restrict__ A, const bf16_t* __restrict__ Bt,
    bf16_t* __restrict__ moebf,
    const float* __restrict__ gate_t, const float* __restrict__ conn,
    const float* __restrict__ ebias) {
  __shared__ bf16_t As[2][128 * 64];   // 32 KB
  __shared__ bf16_t Bs[6][64 * 64];    // 48 KB

  const int wid = (blockIdx.x & 7) * 32 + (blockIdx.x >> 3);
  const int b0 = (wid & 7) * 128;
  const int n0 = (wid >> 3) * 64;

  const int t = threadIdx.x;
  const int lane = t & 63, wave = t >> 6;
  const int wmh = wave >> 2, wnq = wave & 3;   // 2m x 4n
  const int lr = lane & 15, lk = (lane >> 4) * 8;
  const int csw = (lr & 7) << 3;
  const int srow = lane >> 3;
  const int scol = ((lane & 7) ^ srow) << 3;
  const size_t EB = (size_t)H_DIM * D_DIM;

  const bf16_t* Asrc = A + (size_t)(b0 + wave * 16 + srow) * D_DIM + scol;
  const bf16_t* Bsrc = Bt + (size_t)(n0 + wave * 8 + srow) * D_DIM + scol;

  auto stageA = [&](int buf, int kt) {
    gl_lds16(Asrc + (size_t)kt * 64, &As[buf][(wave * 16) * 64]);
    gl_lds16(Asrc + 8 * D_DIM + (size_t)kt * 64, &As[buf][(wave * 16 + 8) * 64]);
  };
  auto stageB = [&](int slot, int e, int kt) {
    gl_lds16(Bsrc + (size_t)e * EB + (size_t)kt * 64, &Bs[slot][(wave * 8) * 64]);
  };
  auto readB = [&](int slot, bf16x8& r0, bf16x8& r1) {
    const bf16_t* Bb = &Bs[slot][0];
    r0 = *(const bf16x8*)&Bb[(wnq * 16 + lr) * 64 + (lk ^ csw)];
    r1 = *(const bf16x8*)&Bb[(wnq * 16 + lr) * 64 + ((32 + lk) ^ csw)];
  };

  f32x4 acc[8][4];
#pragma unroll
  for (int e = 0; e < 8; ++e)
#pragma unroll
    for (int mf = 0; mf < 4; ++mf) acc[e][mf] = (f32x4){0.f, 0.f, 0.f, 0.f};

  // prologue: A(0) first (FIFO head), then pair for phase 0 (slots 0,1 = experts 0,1 of kt0)
  stageA(0, 0);
  stageB(0, 0, 0);
  stageB(1, 1, 0);

  int rs = 0;   // read slot base = (2P)%6
  int ws = 2;   // stage slot base = (2P+2)%6
  for (int kt = 0; kt < 16; ++kt) {
    const int ab = kt & 1;
    const bool last = (kt == 15);
    bf16x8 af[2][4];
#pragma unroll
    for (int eh = 0; eh < 4; ++eh) {
      const int e0 = eh * 2, e1 = e0 + 1;
      // 1. stage the pair for phase P+1
      if (eh < 3) {
        stageB(ws, e0 + 2, kt);
        stageB(ws + 1, e1 + 2, kt);
      } else if (!last) {
        stageB(ws, 0, kt + 1);
        stageB(ws + 1, 1, kt + 1);
        stageA(ab ^ 1, kt + 1);
      }
      // 2. counted vmcnt: retire exactly this phase's loads (issued at P-1)
      if (eh == 3) {
        if (last) { WAITV(0); } else { WAITV(4); }
      } else {
        WAITV(2);
      }
      // 3. barrier, pinned
      __builtin_amdgcn_s_barrier();
      __builtin_amdgcn_sched_barrier(0);
      // 4. A fragments once per kt
      if (eh == 0) {
#pragma unroll
        for (int kk = 0; kk < 2; ++kk)
#pragma unroll
          for (int mf = 0; mf < 4; ++mf)
            af[kk][mf] = *(const bf16x8*)&As[ab][(wmh * 64 + mf * 16 + lr) * 64 +
                                                ((kk * 32 + lk) ^ csw)];
      }
      // 5. B fragments for this phase, then 16 MFMA
      bf16x8 p0, p1, q0, q1;
      readB(rs, p0, p1);
      readB(rs + 1, q0, q1);
      __builtin_amdgcn_s_setprio(1);
#pragma unroll
      for (int mf = 0; mf < 4; ++mf) {
        acc[e0][mf] = __builtin_amdgcn_mfma_f32_16x16x32_bf16(af[0][mf], p0, acc[e0][mf], 0, 0, 0);
        acc[e0][mf] = __builtin_amdgcn_mfma_f32_16x16x32_bf16(af[1][mf], p1, acc[e0][mf], 0, 0, 0);
      }
#pragma unroll
      for (int mf = 0; mf < 4; ++mf) {
        acc[e1][mf] = __builtin_amdgcn_mfma_f32_16x16x32_bf16(af[0][mf], q0, acc[e1][mf], 0, 0, 0);
        acc[e1][mf] = __builtin_amdgcn_mfma_f32_16x16x32_bf16(af[1][mf], q1, acc[e1][mf], 0, 0, 0);
      }
      __builtin_amdgcn_s_setprio(0);
      rs = (rs >= 4) ? rs - 4 : rs + 2;   // +2 mod 6
      ws = (ws >= 4) ? ws - 4 : ws + 2;
    }
  }

  const int r4 = (lane >> 4) * 4;
  const int gcol = n0 + wnq * 16 + lr;
  const int growb = b0 + wmh * 64;
  f32x4 sum[4];
#pragma unroll
  for (int mf = 0; mf < 4; ++mf) sum[mf] = (f32x4){0.f, 0.f, 0.f, 0.f};
#pragma unroll
  for (int e = 0; e < 8; ++e) {
    const float cm = conn[e * H_DIM + gcol];
    const float bb = ebias[e * H_DIM + gcol];
#pragma unroll
    for (int mf = 0; mf < 4; ++mf) {
      const float4 g4 = *(const float4*)&gate_t[e * B_DIM + growb + mf * 16 + r4];
      sum[mf][0] += fmaxf((acc[e][mf][0] + bb) * cm, 0.f) * g4.x;
      sum[mf][1] += fmaxf((acc[e][mf][1] + bb) * cm, 0.f) * g4.y;
      sum[mf][2] += fmaxf((acc[e][mf][2] + bb) * cm, 0.f) * g4.z;
      sum[mf][3] += fmaxf((acc[e][mf][3] + bb) * cm, 0.f) * g4.w;
    }
  }
#pragma unroll
  for (int mf = 0; mf < 4; ++mf)
#pragma unroll
    for (int j = 0; j < 4; ++j) {
      const int grow = growb + mf * 16 + r4 + j;
      moebf[(size_t)grow * H_DIM + gcol] = (bf16_t)sum[mf][j];
    }
}

// ---------------- stage-2 GEMM: 128x64 tile, 8 waves (4m x 2n), split-K x2, grid 512 ------
template <typename OT>
__global__ __launch_bounds__(512, 2) void gemm_sk2(
    const bf16_t* __restrict__ A, const bf16_t* __restrict__ Bt, OT* __restrict__ C) {
  __shared__ bf16_t As[2][128 * 64];   // 16 KB x2
  __shared__ bf16_t Bs[2][64 * 64];    // 8 KB x2

  const int wid = (blockIdx.x & 7) * 64 + (blockIdx.x >> 3);
  const int ez = wid >> 8;          // split-K half
  const int rem = wid & 255;
  const int b0 = (rem & 7) * 128;
  const int n0 = (rem >> 3) * 64;
  const int kbase = ez << 10;

  const int t = threadIdx.x;
  const int lane = t & 63, wave = t >> 6;
  const int wm = wave >> 1, wn = wave & 1;   // 4m x 2n, wave tile 32x32
  const int lr = lane & 15, lk = (lane >> 4) * 8;
  const int csw = (lr & 7) << 3;
  const int srow = lane >> 3;
  const int scol = ((lane & 7) ^ srow) << 3;

  const bf16_t* Arow = A + (size_t)(b0 + wave * 16 + srow) * 2048 + kbase + scol;
  const bf16_t* Brow = Bt + (size_t)(n0 + wave * 8 + srow) * 2048 + kbase + scol;

  const f32x4 zv = {0.f, 0.f, 0.f, 0.f};
  f32x4 acc[2][2];
#pragma unroll
  for (int mf = 0; mf < 2; ++mf)
#pragma unroll
    for (int nf = 0; nf < 2; ++nf) acc[mf][nf] = zv;

  auto STAGE = [&](int bsel, int kt) {
    const int ko = kt << 6;
    gl_lds16(Arow + ko, &As[bsel][(wave * 16) * 64]);
    gl_lds16(Arow + (size_t)8 * 2048 + ko, &As[bsel][(wave * 16 + 8) * 64]);
    gl_lds16(Brow + ko, &Bs[bsel][(wave * 8) * 64]);
  };

  auto COMPUTE = [&](int bsel) {
    bf16x8 bfr[2][2], afr[2][2];
#pragma unroll
    for (int kk = 0; kk < 2; ++kk) {
#pragma unroll
      for (int nf = 0; nf < 2; ++nf)
        bfr[kk][nf] = *(const bf16x8*)&Bs[bsel][(wn * 32 + nf * 16 + lr) * 64 + ((kk * 32 + lk) ^ csw)];
#pragma unroll
      for (int mf = 0; mf < 2; ++mf)
        afr[kk][mf] = *(const bf16x8*)&As[bsel][(wm * 32 + mf * 16 + lr) * 64 + ((kk * 32 + lk) ^ csw)];
    }
    __builtin_amdgcn_s_setprio(1);
#pragma unroll
    for (int mf = 0; mf < 2; ++mf)
#pragma unroll
      for (int nf = 0; nf < 2; ++nf) {
        acc[mf][nf] = __builtin_amdgcn_mfma_f32_16x16x32_bf16(afr[0][mf], bfr[0][nf], acc[mf][nf], 0, 0, 0);
        acc[mf][nf] = __builtin_amdgcn_mfma_f32_16x16x32_bf16(afr[1][mf], bfr[1][nf], acc[mf][nf], 0, 0, 0);
      }
    __builtin_amdgcn_s_setprio(0);
  };

  STAGE(0, 0);
  __syncthreads();
  for (int kt = 0; kt < 15; ++kt) {
    STAGE((kt + 1) & 1, kt + 1);
    COMPUTE(kt & 1);
    __syncthreads();
  }
  COMPUTE(1);

  const int r4 = (lane >> 4) * 4;
#pragma unroll
  for (int mf = 0; mf < 2; ++mf) {
#pragma unroll
    for (int nf = 0; nf < 2; ++nf) {
      int gcol = n0 + wn * 32 + nf * 16 + lr;
#pragma unroll
      for (int j = 0; j < 4; ++j) {
        int grow = b0 + wm * 32 + mf * 16 + r4 + j;
        C[((size_t)ez * B_DIM + grow) * 2048 + gcol] = (OT)acc[mf][nf][j];
      }
    }
  }
}

// ---------------- softmax over M: sum 2 bf16 split-K partials + bias -> bf16 attn -----------
__global__ __launch_bounds__(256) void softmax_kernel(
    const bf16_t* __restrict__ lg, const float* __restrict__ bias, bf16_t* __restrict__ attn) {
  const size_t P = (size_t)B_DIM * M_DIM;
  int b = blockIdx.x, t = threadIdx.x;
  int lane = t & 63, wave = t >> 6;
  __shared__ float rmax[4], rsum[4];
  float v[8];
  float m = -1e30f;
#pragma unroll
  for (int i = 0; i < 8; ++i) {
    size_t idx = (size_t)b * M_DIM + i * 256 + t;
    v[i] = (float)lg[idx] + (float)lg[P + idx] + bias[i * 256 + t];
    m = fmaxf(m, v[i]);
  }
#pragma unroll
  for (int off = 32; off >= 1; off >>= 1) m = fmaxf(m, __shfl_xor(m, off));
  if (lane == 0) rmax[wave] = m;
  __syncthreads();
  m = fmaxf(fmaxf(rmax[0], rmax[1]), fmaxf(rmax[2], rmax[3]));
  float s = 0.f;
#pragma unroll
  for (int i = 0; i < 8; ++i) {
    v[i] = __expf(v[i] - m);
    s += v[i];
  }
#pragma unroll
  for (int off = 32; off >= 1; off >>= 1) s += __shfl_xor(s, off);
  if (lane == 0) rsum[wave] = s;
  __syncthreads();
  s = rsum[0] + rsum[1] + rsum[2] + rsum[3];
  float inv = 1.f / s;
#pragma unroll
  for (int i = 0; i < 8; ++i) attn[(size_t)b * M_DIM + i * 256 + t] = (bf16_t)(v[i] * inv);
}

// ---------------- final act: out = act(moe_bf + sum of 2 bf16 readv partials) --------------
__global__ __launch_bounds__(256) void act_kernel(
    const bf16_t* __restrict__ moebf, const bf16_t* __restrict__ rdv,
    const float* __restrict__ aw, float* __restrict__ out) {
  const size_t P = (size_t)B_DIM * H_DIM;
  int i = blockIdx.x * 256 + threadIdx.x;
  float w[9], m = -1e30f;
#pragma unroll
  for (int j = 0; j < 9; ++j) { w[j] = aw[j]; m = fmaxf(m, w[j]); }
  float p[9], s = 0.f;
#pragma unroll
  for (int j = 0; j < 9; ++j) { p[j] = expf(w[j] - m); s += p[j]; }
  float inv = 1.f / s;
#pragma unroll
  for (int j = 0; j < 9; ++j) p[j] *= inv;
  bf16x4 mv = *(const bf16x4*)&moebf[(size_t)i * 4];
  bf16x4 r0 = *(const bf16x4*)&rdv[(size_t)i * 4];
  bf16x4 r1 = *(const bf16x4*)&rdv[P + (size_t)i * 4];
  float xs[4] = {(float)mv[0] + (float)r0[0] + (float)r1[0],
                 (float)mv[1] + (float)r0[1] + (float)r1[1],
                 (float)mv[2] + (float)r0[2] + (float)r1[2],
                 (float)mv[3] + (float)r0[3] + (float)r1[3]};
  float os[4];
#pragma unroll
  for (int q = 0; q < 4; ++q) {
    float xv = xs[q];
    float enx = expf(-xv);
    float ex = expf(xv);
    float sig = 1.f / (1.f + enx);
    float em1 = expm1f(xv);
    float th = tanhf(xv);
    float rl = fmaxf(xv, 0.f);
    float si = xv * sig;
    float ge = 0.5f * xv * (1.f + erff(xv * 0.70710678118654752f));
    float se = 1.0507009873554805f * (xv > 0.f ? xv : 1.6732632423543772f * em1);
    float el = xv > 0.f ? xv : em1;
    float sp = log1pf(ex);
    float mi = xv * tanhf(sp);
    os[q] = p[0] * sig + p[1] * el + p[2] * th + p[3] * rl + p[4] * si + p[5] * ge + p[6] * se + p[7] * mi;
  }
  ((float4*)out)[i] = make_float4(os[0], os[1], os[2], os[3]);
}

extern "C" void kernel_launch(void* const* d_in, const int* in_sizes, int n_in,
                              void* d_out, int out_size, void* d_ws, size_t ws_size,
                              hipStream_t stream) {
  const float* x        = (const float*)d_in[0];
  const float* gate_w   = (const float*)d_in[1];
  const float* expert_w = (const float*)d_in[2];
  const float* expert_b = (const float*)d_in[3];
  const float* conn_w1  = (const float*)d_in[4];
  const float* conn_b1  = (const float*)d_in[5];
  const float* conn_w2  = (const float*)d_in[6];
  const float* conn_b2  = (const float*)d_in[7];
  const float* navg     = (const float*)d_in[8];
  const float* nmask    = (const float*)d_in[9];
  const float* mem_rw   = (const float*)d_in[10];
  const float* mem_rb   = (const float*)d_in[11];
  const float* memory   = (const float*)d_in[12];
  const float* act_w    = (const float*)d_in[13];
  float* out = (float*)d_out;

  char* ws = (char*)d_ws;
  // persistent-within-call buffers
  bf16_t* wbT    = (bf16_t*)(ws + 0);            // [E][H][D] 33554432
  bf16_t* mrT    = (bf16_t*)(ws + 33554432);     // [M][H] 8388608
  bf16_t* memT   = (bf16_t*)(ws + 41943040);     // [H][M] 8388608
  float*  gate_t = (float*)(ws + 50331648);      // [E][B] 32768
  float*  connb  = (float*)(ws + 50364416);      // [E][H] 65536
  bf16_t* x_bf   = (bf16_t*)(ws + 50429952);     // 2097152 (ends 52527104)
  bf16_t* moe_bf = (bf16_t*)(ws + 52527104);     // 4194304 (ends 56721408)
  // aliases (regions dead by the time these are written)
  bf16_t* logits = (bf16_t*)(ws + 0);            // [2][B][M] bf16 8388608 (wbT dead)
  bf16_t* attn   = (bf16_t*)(ws + 8388608);      // 4194304 (ends 12582912)
  bf16_t* readv  = (bf16_t*)(ws + 0);            // [2][B][H] bf16 8388608 (logits dead)

  // 1. prep (transposes + gate/cvt) and separate conn
  prep_kernel<<<dim3(4096), 256, 0, stream>>>(expert_w, mem_rw, memory, wbT, mrT, memT,
                                              x, gate_w, gate_t, x_bf);
  conn_kernel<<<dim3(64), 256, 0, stream>>>(navg, conn_w1, conn_b1, conn_w2, conn_b2, nmask, connb);
  // 2. expert GEMM, ring-6 distance-1 pair-phase (2 blocks/CU), writes moe_bf only
  expert_gemm<<<dim3(256), 512, 0, stream>>>(x_bf, wbT, moe_bf, gate_t, connb, expert_b);
  // 3. memory attention: split-K2 GEMMs -> bf16 partials, fused sums downstream
  gemm_sk2<bf16_t><<<dim3(512), 512, 0, stream>>>(moe_bf, mrT, logits);
  softmax_kernel<<<dim3(B_DIM), 256, 0, stream>>>(logits, mem_rb, attn);
  gemm_sk2<bf16_t><<<dim3(512), 512, 0, stream>>>(attn, memT, readv);
  // 4. blended activation (reads moe_bf + bf16 readv partials, writes d_out)
  act_kernel<<<dim3((B_DIM * H_DIM) / (256 * 4)), 256, 0, stream>>>(moe_bf, readv, act_w, out);
}

// Round 21
// 129.477 us; speedup vs baseline: 1.0564x; 1.0564x over previous
//
#include <hip/hip_runtime.h>
#include <hip/hip_bf16.h>
#include <math.h>

typedef __bf16 bf16_t;
typedef __bf16 bf16x8 __attribute__((ext_vector_type(8)));
typedef __bf16 bf16x4 __attribute__((ext_vector_type(4)));
typedef float f32x4 __attribute__((ext_vector_type(4)));

#define B_DIM 1024
#define D_DIM 1024
#define H_DIM 2048
#define E_DIM 8
#define M_DIM 2048

typedef const __attribute__((address_space(1))) unsigned int as1_uint;
typedef __attribute__((address_space(3))) unsigned int as3_uint;

__device__ __forceinline__ void gl_lds16(const void* g, void* l) {
  __builtin_amdgcn_global_load_lds((as1_uint*)g, (as3_uint*)l, 16, 0, 0);
}

#define WAITV(n) asm volatile("s_waitcnt vmcnt(" #n ")" ::: "memory")

// ---------------- prep: transpose 128x64 (0..3071), gate+cvt (3072..4095) ------------------
__global__ __launch_bounds__(256, 6) void prep_kernel(
    const float* __restrict__ ew, const float* __restrict__ mrw, const float* __restrict__ mem,
    bf16_t* __restrict__ wbT, bf16_t* __restrict__ mrT, bf16_t* __restrict__ memT,
    const float* __restrict__ x, const float* __restrict__ gw,
    float* __restrict__ gate_t, bf16_t* __restrict__ x_bf) {
  __shared__ char smem[16384];
  const int bid = blockIdx.x;
  const int t = threadIdx.x;

  if (bid < 3072) {
    bf16_t* tile = (bf16_t*)smem;   // [128][64] elem, addr = r*64 + (c ^ ((r>>3)&7)<<2)
    const float* in; bf16_t* out; int R, C, rt, ct;
    if (bid < 2048) {
      int slab = bid >> 8, rem = bid & 255;
      in = ew + (size_t)slab * D_DIM * H_DIM; out = wbT + (size_t)slab * D_DIM * H_DIM;
      R = D_DIM; C = H_DIM; rt = rem >> 5; ct = rem & 31;
    } else if (bid < 2560) {
      int rem = bid - 2048;
      in = mrw; out = mrT; R = H_DIM; C = M_DIM; rt = rem >> 5; ct = rem & 31;
    } else {
      int rem = bid - 2560;
      in = mem; out = memT; R = M_DIM; C = H_DIM; rt = rem >> 5; ct = rem & 31;
    }
    const int r0 = rt * 128, c0 = ct * 64;
    int cq = (t & 15) * 4, rr = t >> 4;
#pragma unroll
    for (int i = 0; i < 8; ++i) {
      int r = rr + 16 * i;
      float4 v = *(const float4*)&in[(size_t)(r0 + r) * C + c0 + cq];
      bf16x4 b;
      b[0] = (bf16_t)v.x; b[1] = (bf16_t)v.y; b[2] = (bf16_t)v.z; b[3] = (bf16_t)v.w;
      *(bf16x4*)&tile[r * 64 + (cq ^ (((r >> 3) & 7) << 2))] = b;
    }
    __syncthreads();
    int r8 = (t & 15) * 8, cc = t >> 4;
    const int sw = (t & 7) << 2;   // = ((r8>>3)&7)<<2, constant over j
#pragma unroll
    for (int i = 0; i < 4; ++i) {
      int c = cc + 16 * i;
      bf16x8 o;
#pragma unroll
      for (int j = 0; j < 8; ++j) o[j] = tile[(r8 + j) * 64 + (c ^ sw)];
      *(bf16x8*)&out[(size_t)(c0 + c) * R + r0 + r8] = o;
    }
  } else {
    // gate + x cvt
    float (*red)[8] = (float(*)[8])smem;   // 8 KB
    int b = bid - 3072;
    float4 v = ((const float4*)(x + (size_t)b * D_DIM))[t];
    bf16x4 xb;
    xb[0] = (bf16_t)v.x; xb[1] = (bf16_t)v.y; xb[2] = (bf16_t)v.z; xb[3] = (bf16_t)v.w;
    *(bf16x4*)&x_bf[(size_t)b * D_DIM + t * 4] = xb;
    float acc[8];
#pragma unroll
    for (int e = 0; e < 8; ++e)
      acc[e] = v.x * gw[(4 * t) * 8 + e] + v.y * gw[(4 * t + 1) * 8 + e] +
               v.z * gw[(4 * t + 2) * 8 + e] + v.w * gw[(4 * t + 3) * 8 + e];
#pragma unroll
    for (int e = 0; e < 8; ++e) red[t][e] = acc[e];
    __syncthreads();
    for (int s = 128; s > 0; s >>= 1) {
      if (t < s) {
#pragma unroll
        for (int e = 0; e < 8; ++e) red[t][e] += red[t + s][e];
      }
      __syncthreads();
    }
    if (t == 0) {
      float m = red[0][0];
#pragma unroll
      for (int e = 1; e < 8; ++e) m = fmaxf(m, red[0][e]);
      float p[8], sum = 0.f;
#pragma unroll
      for (int e = 0; e < 8; ++e) { p[e] = expf(red[0][e] - m); sum += p[e]; }
      float inv = 1.f / sum;
#pragma unroll
      for (int e = 0; e < 8; ++e) gate_t[e * B_DIM + b] = p[e] * inv;
    }
  }
}

// ---------------- conn (separate, single dispatch): 64 blocks (e,c); full h1 each ----------
__global__ __launch_bounds__(256) void conn_kernel(
    const float* __restrict__ avg, const float* __restrict__ w1, const float* __restrict__ b1,
    const float* __restrict__ w2, const float* __restrict__ b2,
    const float* __restrict__ mask, float* __restrict__ conn) {
  __shared__ float red[256 * 32];
  __shared__ float h1[32];
  int e = blockIdx.x >> 3, c = blockIdx.x & 7, t = threadIdx.x;
  float acc[32];
#pragma unroll
  for (int k = 0; k < 32; ++k) acc[k] = 0.f;
#pragma unroll
  for (int i = 0; i < 8; ++i) {
    int h = i * 256 + t;
    float av = avg[e * H_DIM + h];
    const float* w1p = &w1[((size_t)e * H_DIM + h) * 32];
#pragma unroll
    for (int k = 0; k < 32; ++k) acc[k] += av * w1p[k];
  }
#pragma unroll
  for (int k = 0; k < 32; ++k) red[t * 32 + k] = acc[k];
  __syncthreads();
  for (int s = 128; s > 0; s >>= 1) {
    if (t < s) {
#pragma unroll
      for (int k = 0; k < 32; ++k) red[t * 32 + k] += red[(t + s) * 32 + k];
    }
    __syncthreads();
  }
  if (t < 32) h1[t] = fmaxf(red[t] + b1[e * 32 + t], 0.f);
  __syncthreads();
  int h = c * 256 + t;
  float s = b2[e * H_DIM + h];
#pragma unroll
  for (int k = 0; k < 32; ++k) s += h1[k] * w2[((size_t)e * 32 + k) * H_DIM + h];
  conn[e * H_DIM + h] = (1.f / (1.f + expf(-s))) * mask[e * H_DIM + h];
}

// ---------------- expert GEMM: 128x64 tile, 8 waves, 8 experts in registers (pair-phase) ----
// Ring-8 slots, stage distance 2 pair-phases (proven R9-R18 schedule).
__global__ __launch_bounds__(512, 2) void expert_gemm(
    const bf16_t* __restrict__ A, const bf16_t* __restrict__ Bt,
    bf16_t* __restrict__ moebf,
    const float* __restrict__ gate_t, const float* __restrict__ conn,
    const float* __restrict__ ebias) {
  __shared__ bf16_t As[2][128 * 64];   // 32 KB
  __shared__ bf16_t Bs[8][64 * 64];    // 64 KB

  const int wid = (blockIdx.x & 7) * 32 + (blockIdx.x >> 3);
  const int b0 = (wid & 7) * 128;
  const int n0 = (wid >> 3) * 64;

  const int t = threadIdx.x;
  const int lane = t & 63, wave = t >> 6;
  const int wmh = wave >> 2, wnq = wave & 3;   // 2m x 4n
  const int lr = lane & 15, lk = (lane >> 4) * 8;
  const int csw = (lr & 7) << 3;
  const int srow = lane >> 3;
  const int scol = ((lane & 7) ^ srow) << 3;
  const size_t EB = (size_t)H_DIM * D_DIM;

  const bf16_t* Asrc = A + (size_t)(b0 + wave * 16 + srow) * D_DIM + scol;
  const bf16_t* Bsrc = Bt + (size_t)(n0 + wave * 8 + srow) * D_DIM + scol;

  auto stageA = [&](int buf, int kt) {
    gl_lds16(Asrc + (size_t)kt * 64, &As[buf][(wave * 16) * 64]);
    gl_lds16(Asrc + 8 * D_DIM + (size_t)kt * 64, &As[buf][(wave * 16 + 8) * 64]);
  };
  auto stageB = [&](int slot, int e, int kt) {
    gl_lds16(Bsrc + (size_t)e * EB + (size_t)kt * 64, &Bs[slot][(wave * 8) * 64]);
  };
  auto readB = [&](int slot, bf16x8& r0, bf16x8& r1) {
    const bf16_t* Bb = &Bs[slot][0];
    r0 = *(const bf16x8*)&Bb[(wnq * 16 + lr) * 64 + (lk ^ csw)];
    r1 = *(const bf16x8*)&Bb[(wnq * 16 + lr) * 64 + ((32 + lk) ^ csw)];
  };

  f32x4 acc[8][4];
#pragma unroll
  for (int e = 0; e < 8; ++e)
#pragma unroll
    for (int mf = 0; mf < 4; ++mf) acc[e][mf] = (f32x4){0.f, 0.f, 0.f, 0.f};

  // prologue: A(0) first, then B slots 0..3 of kt0 (FIFO: [A,A,B0,B1,B2,B3])
  stageA(0, 0);
  stageB(0, 0, 0);
  stageB(1, 1, 0);
  stageB(2, 2, 0);
  stageB(3, 3, 0);

  for (int kt = 0; kt < 16; ++kt) {
    const int ab = kt & 1;
    const bool last = (kt == 15);
    bf16x8 af[2][4];
#pragma unroll
    for (int eh = 0; eh < 4; ++eh) {
      const int e0 = eh * 2, e1 = e0 + 1;
      if (eh < 2) {
        stageB(e0 + 4, e0 + 4, kt);
        stageB(e1 + 4, e1 + 4, kt);
      } else if (!last) {
        stageB(e0 - 4, e0 - 4, kt + 1);
        stageB(e1 - 4, e1 - 4, kt + 1);
        if (eh == 2) stageA(ab ^ 1, kt + 1);
      }
      if (eh < 2)        { WAITV(4); }
      else if (!last)    { WAITV(6); }
      else if (eh == 2)  { WAITV(2); }
      else               { WAITV(0); }
      __builtin_amdgcn_s_barrier();
      __builtin_amdgcn_sched_barrier(0);
      if (eh == 0) {
#pragma unroll
        for (int kk = 0; kk < 2; ++kk)
#pragma unroll
          for (int mf = 0; mf < 4; ++mf)
            af[kk][mf] = *(const bf16x8*)&As[ab][(wmh * 64 + mf * 16 + lr) * 64 +
                                                ((kk * 32 + lk) ^ csw)];
      }
      bf16x8 p0, p1, q0, q1;
      readB(e0, p0, p1);
      readB(e1, q0, q1);
      __builtin_amdgcn_s_setprio(1);
#pragma unroll
      for (int mf = 0; mf < 4; ++mf) {
        acc[e0][mf] = __builtin_amdgcn_mfma_f32_16x16x32_bf16(af[0][mf], p0, acc[e0][mf], 0, 0, 0);
        acc[e0][mf] = __builtin_amdgcn_mfma_f32_16x16x32_bf16(af[1][mf], p1, acc[e0][mf], 0, 0, 0);
      }
#pragma unroll
      for (int mf = 0; mf < 4; ++mf) {
        acc[e1][mf] = __builtin_amdgcn_mfma_f32_16x16x32_bf16(af[0][mf], q0, acc[e1][mf], 0, 0, 0);
        acc[e1][mf] = __builtin_amdgcn_mfma_f32_16x16x32_bf16(af[1][mf], q1, acc[e1][mf], 0, 0, 0);
      }
      __builtin_amdgcn_s_setprio(0);
    }
  }

  const int r4 = (lane >> 4) * 4;
  const int gcol = n0 + wnq * 16 + lr;
  const int growb = b0 + wmh * 64;
  f32x4 sum[4];
#pragma unroll
  for (int mf = 0; mf < 4; ++mf) sum[mf] = (f32x4){0.f, 0.f, 0.f, 0.f};
#pragma unroll
  for (int e = 0; e < 8; ++e) {
    const float cm = conn[e * H_DIM + gcol];
    const float bb = ebias[e * H_DIM + gcol];
#pragma unroll
    for (int mf = 0; mf < 4; ++mf) {
      const float4 g4 = *(const float4*)&gate_t[e * B_DIM + growb + mf * 16 + r4];
      sum[mf][0] += fmaxf((acc[e][mf][0] + bb) * cm, 0.f) * g4.x;
      sum[mf][1] += fmaxf((acc[e][mf][1] + bb) * cm, 0.f) * g4.y;
      sum[mf][2] += fmaxf((acc[e][mf][2] + bb) * cm, 0.f) * g4.z;
      sum[mf][3] += fmaxf((acc[e][mf][3] + bb) * cm, 0.f) * g4.w;
    }
  }
#pragma unroll
  for (int mf = 0; mf < 4; ++mf)
#pragma unroll
    for (int j = 0; j < 4; ++j) {
      const int grow = growb + mf * 16 + r4 + j;
      moebf[(size_t)grow * H_DIM + gcol] = (bf16_t)sum[mf][j];
    }
}

// ---------------- stage-2 GEMM: 128x64 tile, 8 waves (4m x 2n), split-K x2, grid 512 ------
template <typename OT>
__global__ __launch_bounds__(512, 2) void gemm_sk2(
    const bf16_t* __restrict__ A, const bf16_t* __restrict__ Bt, OT* __restrict__ C) {
  __shared__ bf16_t As[2][128 * 64];   // 16 KB x2
  __shared__ bf16_t Bs[2][64 * 64];    // 8 KB x2

  const int wid = (blockIdx.x & 7) * 64 + (blockIdx.x >> 3);
  const int ez = wid >> 8;          // split-K half
  const int rem = wid & 255;
  const int b0 = (rem & 7) * 128;
  const int n0 = (rem >> 3) * 64;
  const int kbase = ez << 10;

  const int t = threadIdx.x;
  const int lane = t & 63, wave = t >> 6;
  const int wm = wave >> 1, wn = wave & 1;   // 4m x 2n, wave tile 32x32
  const int lr = lane & 15, lk = (lane >> 4) * 8;
  const int csw = (lr & 7) << 3;
  const int srow = lane >> 3;
  const int scol = ((lane & 7) ^ srow) << 3;

  const bf16_t* Arow = A + (size_t)(b0 + wave * 16 + srow) * 2048 + kbase + scol;
  const bf16_t* Brow = Bt + (size_t)(n0 + wave * 8 + srow) * 2048 + kbase + scol;

  const f32x4 zv = {0.f, 0.f, 0.f, 0.f};
  f32x4 acc[2][2];
#pragma unroll
  for (int mf = 0; mf < 2; ++mf)
#pragma unroll
    for (int nf = 0; nf < 2; ++nf) acc[mf][nf] = zv;

  auto STAGE = [&](int bsel, int kt) {
    const int ko = kt << 6;
    gl_lds16(Arow + ko, &As[bsel][(wave * 16) * 64]);
    gl_lds16(Arow + (size_t)8 * 2048 + ko, &As[bsel][(wave * 16 + 8) * 64]);
    gl_lds16(Brow + ko, &Bs[bsel][(wave * 8) * 64]);
  };

  auto COMPUTE = [&](int bsel) {
    bf16x8 bfr[2][2], afr[2][2];
#pragma unroll
    for (int kk = 0; kk < 2; ++kk) {
#pragma unroll
      for (int nf = 0; nf < 2; ++nf)
        bfr[kk][nf] = *(const bf16x8*)&Bs[bsel][(wn * 32 + nf * 16 + lr) * 64 + ((kk * 32 + lk) ^ csw)];
#pragma unroll
      for (int mf = 0; mf < 2; ++mf)
        afr[kk][mf] = *(const bf16x8*)&As[bsel][(wm * 32 + mf * 16 + lr) * 64 + ((kk * 32 + lk) ^ csw)];
    }
    __builtin_amdgcn_s_setprio(1);
#pragma unroll
    for (int mf = 0; mf < 2; ++mf)
#pragma unroll
      for (int nf = 0; nf < 2; ++nf) {
        acc[mf][nf] = __builtin_amdgcn_mfma_f32_16x16x32_bf16(afr[0][mf], bfr[0][nf], acc[mf][nf], 0, 0, 0);
        acc[mf][nf] = __builtin_amdgcn_mfma_f32_16x16x32_bf16(afr[1][mf], bfr[1][nf], acc[mf][nf], 0, 0, 0);
      }
    __builtin_amdgcn_s_setprio(0);
  };

  STAGE(0, 0);
  __syncthreads();
  for (int kt = 0; kt < 15; ++kt) {
    STAGE((kt + 1) & 1, kt + 1);
    COMPUTE(kt & 1);
    __syncthreads();
  }
  COMPUTE(1);

  const int r4 = (lane >> 4) * 4;
#pragma unroll
  for (int mf = 0; mf < 2; ++mf) {
#pragma unroll
    for (int nf = 0; nf < 2; ++nf) {
      int gcol = n0 + wn * 32 + nf * 16 + lr;
#pragma unroll
      for (int j = 0; j < 4; ++j) {
        int grow = b0 + wm * 32 + mf * 16 + r4 + j;
        C[((size_t)ez * B_DIM + grow) * 2048 + gcol] = (OT)acc[mf][nf][j];
      }
    }
  }
}

// ---------------- softmax over M: sum 2 bf16 split-K partials + bias -> bf16 attn -----------
__global__ __launch_bounds__(256) void softmax_kernel(
    const bf16_t* __restrict__ lg, const float* __restrict__ bias, bf16_t* __restrict__ attn) {
  const size_t P = (size_t)B_DIM * M_DIM;
  int b = blockIdx.x, t = threadIdx.x;
  int lane = t & 63, wave = t >> 6;
  __shared__ float rmax[4], rsum[4];
  float v[8];
  float m = -1e30f;
#pragma unroll
  for (int i = 0; i < 8; ++i) {
    size_t idx = (size_t)b * M_DIM + i * 256 + t;
    v[i] = (float)lg[idx] + (float)lg[P + idx] + bias[i * 256 + t];
    m = fmaxf(m, v[i]);
  }
#pragma unroll
  for (int off = 32; off >= 1; off >>= 1) m = fmaxf(m, __shfl_xor(m, off));
  if (lane == 0) rmax[wave] = m;
  __syncthreads();
  m = fmaxf(fmaxf(rmax[0], rmax[1]), fmaxf(rmax[2], rmax[3]));
  float s = 0.f;
#pragma unroll
  for (int i = 0; i < 8; ++i) {
    v[i] = __expf(v[i] - m);
    s += v[i];
  }
#pragma unroll
  for (int off = 32; off >= 1; off >>= 1) s += __shfl_xor(s, off);
  if (lane == 0) rsum[wave] = s;
  __syncthreads();
  s = rsum[0] + rsum[1] + rsum[2] + rsum[3];
  float inv = 1.f / s;
#pragma unroll
  for (int i = 0; i < 8; ++i) attn[(size_t)b * M_DIM + i * 256 + t] = (bf16_t)(v[i] * inv);
}

// ---------------- final act: out = act(moe_bf + sum of 2 bf16 readv partials) --------------
__global__ __launch_bounds__(256) void act_kernel(
    const bf16_t* __restrict__ moebf, const bf16_t* __restrict__ rdv,
    const float* __restrict__ aw, float* __restrict__ out) {
  const size_t P = (size_t)B_DIM * H_DIM;
  int i = blockIdx.x * 256 + threadIdx.x;
  float w[9], m = -1e30f;
#pragma unroll
  for (int j = 0; j < 9; ++j) { w[j] = aw[j]; m = fmaxf(m, w[j]); }
  float p[9], s = 0.f;
#pragma unroll
  for (int j = 0; j < 9; ++j) { p[j] = expf(w[j] - m); s += p[j]; }
  float inv = 1.f / s;
#pragma unroll
  for (int j = 0; j < 9; ++j) p[j] *= inv;
  bf16x4 mv = *(const bf16x4*)&moebf[(size_t)i * 4];
  bf16x4 r0 = *(const bf16x4*)&rdv[(size_t)i * 4];
  bf16x4 r1 = *(const bf16x4*)&rdv[P + (size_t)i * 4];
  float xs[4] = {(float)mv[0] + (float)r0[0] + (float)r1[0],
                 (float)mv[1] + (float)r0[1] + (float)r1[1],
                 (float)mv[2] + (float)r0[2] + (float)r1[2],
                 (float)mv[3] + (float)r0[3] + (float)r1[3]};
  float os[4];
#pragma unroll
  for (int q = 0; q < 4; ++q) {
    float xv = xs[q];
    float enx = expf(-xv);
    float ex = expf(xv);
    float sig = 1.f / (1.f + enx);
    float em1 = expm1f(xv);
    float th = tanhf(xv);
    float rl = fmaxf(xv, 0.f);
    float si = xv * sig;
    float ge = 0.5f * xv * (1.f + erff(xv * 0.70710678118654752f));
    float se = 1.0507009873554805f * (xv > 0.f ? xv : 1.6732632423543772f * em1);
    float el = xv > 0.f ? xv : em1;
    float sp = log1pf(ex);
    float mi = xv * tanhf(sp);
    os[q] = p[0] * sig + p[1] * el + p[2] * th + p[3] * rl + p[4] * si + p[5] * ge + p[6] * se + p[7] * mi;
  }
  ((float4*)out)[i] = make_float4(os[0], os[1], os[2], os[3]);
}

extern "C" void kernel_launch(void* const* d_in, const int* in_sizes, int n_in,
                              void* d_out, int out_size, void* d_ws, size_t ws_size,
                              hipStream_t stream) {
  const float* x        = (const float*)d_in[0];
  const float* gate_w   = (const float*)d_in[1];
  const float* expert_w = (const float*)d_in[2];
  const float* expert_b = (const float*)d_in[3];
  const float* conn_w1  = (const float*)d_in[4];
  const float* conn_b1  = (const float*)d_in[5];
  const float* conn_w2  = (const float*)d_in[6];
  const float* conn_b2  = (const float*)d_in[7];
  const float* navg     = (const float*)d_in[8];
  const float* nmask    = (const float*)d_in[9];
  const float* mem_rw   = (const float*)d_in[10];
  const float* mem_rb   = (const float*)d_in[11];
  const float* memory   = (const float*)d_in[12];
  const float* act_w    = (const float*)d_in[13];
  float* out = (float*)d_out;

  char* ws = (char*)d_ws;
  // persistent-within-call buffers
  bf16_t* wbT    = (bf16_t*)(ws + 0);            // [E][H][D] 33554432
  bf16_t* mrT    = (bf16_t*)(ws + 33554432);     // [M][H] 8388608
  bf16_t* memT   = (bf16_t*)(ws + 41943040);     // [H][M] 8388608
  float*  gate_t = (float*)(ws + 50331648);      // [E][B] 32768
  float*  connb  = (float*)(ws + 50364416);      // [E][H] 65536
  bf16_t* x_bf   = (bf16_t*)(ws + 50429952);     // 2097152 (ends 52527104)
  bf16_t* moe_bf = (bf16_t*)(ws + 52527104);     // 4194304 (ends 56721408)
  // aliases (regions dead by the time these are written)
  bf16_t* logits = (bf16_t*)(ws + 0);            // [2][B][M] bf16 8388608 (wbT dead)
  bf16_t* attn   = (bf16_t*)(ws + 8388608);      // 4194304 (ends 12582912)
  bf16_t* readv  = (bf16_t*)(ws + 0);            // [2][B][H] bf16 8388608 (logits dead)

  // 1. prep (transposes + gate/cvt) and separate conn
  prep_kernel<<<dim3(4096), 256, 0, stream>>>(expert_w, mem_rw, memory, wbT, mrT, memT,
                                              x, gate_w, gate_t, x_bf);
  conn_kernel<<<dim3(64), 256, 0, stream>>>(navg, conn_w1, conn_b1, conn_w2, conn_b2, nmask, connb);
  // 2. expert GEMM, ring-8 pair-phase, writes moe_bf only
  expert_gemm<<<dim3(256), 512, 0, stream>>>(x_bf, wbT, moe_bf, gate_t, connb, expert_b);
  // 3. memory attention: split-K2 GEMMs -> bf16 partials, fused sums downstream
  gemm_sk2<bf16_t><<<dim3(512), 512, 0, stream>>>(moe_bf, mrT, logits);
  softmax_kernel<<<dim3(B_DIM), 256, 0, stream>>>(logits, mem_rb, attn);
  gemm_sk2<bf16_t><<<dim3(512), 512, 0, stream>>>(attn, memT, readv);
  // 4. blended activation (reads moe_bf + bf16 readv partials, writes d_out)
  act_kernel<<<dim3((B_DIM * H_DIM) / (256 * 4)), 256, 0, stream>>>(moe_bf, readv, act_w, out);
}